// Round 3
// baseline (70.748 us; speedup 1.0000x reference)
//
#include <hip/hip_runtime.h>
#include <cmath>

// SpikesToTimesDecoder: input [T, B, N] fp32 0/1 raster -> output [3, B, N]
// fp32 times (t * 0.001) of the first 3 spikes per channel, inf-padded.
//
// R1/R2 established we're DRAM-efficiency-bound: dword-per-lane wave-steps
// (256 B granules at 512 KB stride) sustain only ~3.3 TB/s regardless of
// pipeline depth. This version reads float4 per lane (4 consecutive channels
// per thread) so each wave-step is a 1 KB contiguous granule -> higher DRAM
// efficiency. CHUNK=4 timesteps keeps the prefetch-overshoot on early exit
// tiny (12 timesteps/wave ~ 6 MB total).
//
// Per-wave early exit once all 256 channels (64 lanes x 4) have 3 spikes
// (expected exit t ~ 200 of 512 at 5% spike rate).
// Rotating 4-buffer pipeline, all buffer/state indices compile-time
// (named buffers + unrolled loops) -> registers, no scratch.

constexpr int K_SPIKES = 3;
constexpr int CPT = 4;    // channels per thread (one float4)
constexpr int CHUNK = 4;  // timesteps per chunk

__global__ __launch_bounds__(128) void spikes_to_times_kernel(
    const float* __restrict__ in, float* __restrict__ out,
    int BN, int T, float dt) {
  const int tid = blockIdx.x * blockDim.x + threadIdx.x;
  const int c4 = tid * CPT;
  if (c4 >= BN) return;

  const int nchunks = (T + CHUNK - 1) / CHUNK;

  float t0[CPT], t1[CPT], t2[CPT];
  int cnt[CPT];
#pragma unroll
  for (int k = 0; k < CPT; ++k) {
    t0[k] = INFINITY; t1[k] = INFINITY; t2[k] = INFINITY; cnt[k] = 0;
  }

  float4 bA[CHUNK], bB[CHUNK], bC[CHUNK], bD[CHUNK];

  // Issue float4 loads for chunk ci into buffer `dst` (clamped so prefetch
  // past the end reads valid memory; clamped chunks are never processed).
#define LOADC(dst, ci)                                                     \
  do {                                                                     \
    const int cc_ = ((ci) < nchunks) ? (ci) : (nchunks - 1);               \
    _Pragma("unroll") for (int j = 0; j < CHUNK; ++j) {                    \
      dst[j] = *reinterpret_cast<const float4*>(                           \
          in + (size_t)(cc_ * CHUNK + j) * (size_t)BN + c4);               \
    }                                                                      \
  } while (0)

  // Process chunk ci held in buffer `src` (branchless conditional chains,
  // 4 independent channel states per thread).
#define PROC(src, ci)                                                      \
  do {                                                                     \
    if ((ci) < nchunks) {                                                  \
      _Pragma("unroll") for (int j = 0; j < CHUNK; ++j) {                  \
        const int ti_ = (ci) * CHUNK + j;                                  \
        const float tt_ = (float)ti_;                                      \
        const float v_[CPT] = {src[j].x, src[j].y, src[j].z, src[j].w};    \
        _Pragma("unroll") for (int k = 0; k < CPT; ++k) {                  \
          const bool s_ = (v_[k] > 0.0f) && (ti_ < T);                     \
          if (s_ && cnt[k] == 0) t0[k] = tt_;                              \
          if (s_ && cnt[k] == 1) t1[k] = tt_;                              \
          if (s_ && cnt[k] == 2) t2[k] = tt_;                              \
          cnt[k] += s_ ? 1 : 0;                                            \
        }                                                                  \
      }                                                                    \
    }                                                                      \
  } while (0)

#define DONE()                                                             \
  (cnt[0] >= K_SPIKES && cnt[1] >= K_SPIKES && cnt[2] >= K_SPIKES &&       \
   cnt[3] >= K_SPIKES)

  // Prologue: prefetch chunks 0,1,2.
  LOADC(bA, 0);
  LOADC(bB, 1);
  LOADC(bC, 2);

  for (int base = 0; base < nchunks; base += 4) {
    LOADC(bD, base + 3);
    PROC(bA, base + 0);
    if (__all(DONE())) break;

    LOADC(bA, base + 4);
    PROC(bB, base + 1);
    if (__all(DONE())) break;

    LOADC(bB, base + 5);
    PROC(bC, base + 2);
    if (__all(DONE())) break;

    LOADC(bC, base + 6);
    PROC(bD, base + 3);
    if (__all(DONE())) break;
  }

#undef LOADC
#undef PROC
#undef DONE

  const float4 o0 = make_float4(t0[0] * dt, t0[1] * dt, t0[2] * dt, t0[3] * dt);
  const float4 o1 = make_float4(t1[0] * dt, t1[1] * dt, t1[2] * dt, t1[3] * dt);
  const float4 o2 = make_float4(t2[0] * dt, t2[1] * dt, t2[2] * dt, t2[3] * dt);
  *reinterpret_cast<float4*>(out + c4) = o0;
  *reinterpret_cast<float4*>(out + BN + c4) = o1;
  *reinterpret_cast<float4*>(out + 2 * (size_t)BN + c4) = o2;
}

extern "C" void kernel_launch(void* const* d_in, const int* in_sizes, int n_in,
                              void* d_out, int out_size, void* d_ws, size_t ws_size,
                              hipStream_t stream) {
  const float* in = (const float*)d_in[0];
  float* out = (float*)d_out;

  const int BN = out_size / K_SPIKES;  // B * N channels
  const int T = in_sizes[0] / BN;      // timesteps

  const int threads = BN / CPT;        // one thread per 4 channels
  const int block = 128;
  const int grid = (threads + block - 1) / block;
  hipLaunchKernelGGL(spikes_to_times_kernel, dim3(grid), dim3(block), 0, stream,
                     in, out, BN, T, 0.001f);
}

// Round 4
// 68.878 us; speedup vs baseline: 1.0272x; 1.0272x over previous
//
#include <hip/hip_runtime.h>
#include <cmath>

// SpikesToTimesDecoder: input [T, B, N] fp32 0/1 raster -> output [3, B, N]
// fp32 times (t * 0.001) of the first 3 spikes per channel, inf-padded.
//
// Model from R1-R3: scattered 256 B wave-granules cap at ~3.3 TB/s service
// (R1/R2); R3's 1 KB granules never reached their cap because the 4-buffer
// pipeline serialized (T_iter ~ full latency) with only 512 waves.
// This version: CPT=4 (float4 per lane -> 1 KB contiguous per wave-step),
// ping-pong double buffer of CHUNK=16 timesteps. While buffer A (chunk k) is
// processed, buffer B (chunk k+1) is in flight; A is refilled with k+2 right
// after processing -> issue-to-consume distance of one phase, equilibrium
// phase time ~ L/2. 512 waves x 16-32 outstanding float4/lane saturates the
// 1 KB-granule service rate. Exit checks every 8 timesteps; a wave exits when
// all its 256 channels (64 lanes x 4) have 3 spikes (expected t ~ 200 of 512).
// All buffer indices compile-time (unrolled) -> registers, no scratch.

constexpr int K_SPIKES = 3;
constexpr int CPT = 4;     // channels per thread (one float4)
constexpr int CHUNK = 16;  // timesteps per buffer

__global__ __launch_bounds__(64) void spikes_to_times_kernel(
    const float* __restrict__ in, float* __restrict__ out,
    int BN, int T, float dt) {
  const int tid = blockIdx.x * blockDim.x + threadIdx.x;
  const int c4 = tid * CPT;
  if (c4 >= BN) return;

  const int nchunks = (T + CHUNK - 1) / CHUNK;

  float t0[CPT], t1[CPT], t2[CPT];
  int cnt[CPT];
#pragma unroll
  for (int k = 0; k < CPT; ++k) {
    t0[k] = INFINITY; t1[k] = INFINITY; t2[k] = INFINITY; cnt[k] = 0;
  }

  float4 bufA[CHUNK], bufB[CHUNK];

  // Issue CHUNK float4 loads for chunk ci (clamped: prefetch past the end
  // reads the last valid chunk; clamped chunks are never processed).
#define LOADC(dst, ci)                                                     \
  do {                                                                     \
    const int cc_ = ((ci) < nchunks) ? (ci) : (nchunks - 1);               \
    _Pragma("unroll") for (int j = 0; j < CHUNK; ++j) {                    \
      dst[j] = *reinterpret_cast<const float4*>(                           \
          in + (size_t)(cc_ * CHUNK + j) * (size_t)BN + c4);               \
    }                                                                      \
  } while (0)

  // Process 8 timesteps [off, off+8) of chunk ci from buffer `src`.
#define PROC8(src, ci, off)                                                \
  do {                                                                     \
    if ((ci) < nchunks) {                                                  \
      _Pragma("unroll") for (int j = (off); j < (off) + 8; ++j) {          \
        const int ti_ = (ci) * CHUNK + j;                                  \
        const float tt_ = (float)ti_;                                      \
        const float v_[CPT] = {src[j].x, src[j].y, src[j].z, src[j].w};    \
        _Pragma("unroll") for (int k = 0; k < CPT; ++k) {                  \
          const bool s_ = (v_[k] > 0.0f) && (ti_ < T);                     \
          if (s_ && cnt[k] == 0) t0[k] = tt_;                              \
          if (s_ && cnt[k] == 1) t1[k] = tt_;                              \
          if (s_ && cnt[k] == 2) t2[k] = tt_;                              \
          cnt[k] += s_ ? 1 : 0;                                            \
        }                                                                  \
      }                                                                    \
    }                                                                      \
  } while (0)

#define DONE()                                                             \
  (cnt[0] >= K_SPIKES && cnt[1] >= K_SPIKES && cnt[2] >= K_SPIKES &&       \
   cnt[3] >= K_SPIKES)

  // Prologue: chunks 0 and 1 in flight.
  LOADC(bufA, 0);
  LOADC(bufB, 1);

  for (int k = 0; k < nchunks; k += 2) {
    // Process chunk k from A (B's loads for k+1 remain outstanding).
    PROC8(bufA, k, 0);
    if (__all(DONE())) break;
    PROC8(bufA, k, 8);
    if (__all(DONE())) break;
    LOADC(bufA, k + 2);  // refill A with chunk k+2

    // Process chunk k+1 from B (A's loads for k+2 remain outstanding).
    PROC8(bufB, k + 1, 0);
    if (__all(DONE())) break;
    PROC8(bufB, k + 1, 8);
    if (__all(DONE())) break;
    LOADC(bufB, k + 3);  // refill B with chunk k+3
  }

#undef LOADC
#undef PROC8
#undef DONE

  const float4 o0 = make_float4(t0[0] * dt, t0[1] * dt, t0[2] * dt, t0[3] * dt);
  const float4 o1 = make_float4(t1[0] * dt, t1[1] * dt, t1[2] * dt, t1[3] * dt);
  const float4 o2 = make_float4(t2[0] * dt, t2[1] * dt, t2[2] * dt, t2[3] * dt);
  *reinterpret_cast<float4*>(out + c4) = o0;
  *reinterpret_cast<float4*>(out + BN + c4) = o1;
  *reinterpret_cast<float4*>(out + 2 * (size_t)BN + c4) = o2;
}

extern "C" void kernel_launch(void* const* d_in, const int* in_sizes, int n_in,
                              void* d_out, int out_size, void* d_ws, size_t ws_size,
                              hipStream_t stream) {
  const float* in = (const float*)d_in[0];
  float* out = (float*)d_out;

  const int BN = out_size / K_SPIKES;  // B * N channels
  const int T = in_sizes[0] / BN;      // timesteps

  const int threads = BN / CPT;  // one thread per 4 channels
  const int block = 64;
  const int grid = (threads + block - 1) / block;
  hipLaunchKernelGGL(spikes_to_times_kernel, dim3(grid), dim3(block), 0, stream,
                     in, out, BN, T, 0.001f);
}

// Round 5
// 64.419 us; speedup vs baseline: 1.0982x; 1.0692x over previous
//
#include <hip/hip_runtime.h>
#include <cmath>

// SpikesToTimesDecoder: input [T, B, N] fp32 0/1 raster -> output [3, B, N]
// fp32 times (t * 0.001) of the first 3 spikes per channel, inf-padded.
//
// Model from R1-R4 (measured):
//   - chip service for 256 B wave-granule column scans caps at ~3.3 TB/s
//     (R1/R2, MLP-independent) -> CPT=1 designs floor at 27 us.
//   - per-wave service ~4.8 GB/s -> any CPT>1 private-slab design is
//     straggler-tail-doomed (R3/R4 = 70 us = 330 steps x CPT*256B / 4.8GB/s).
// This design breaks the tradeoff: 4 waves COOPERATE on one 256-channel slab.
//   - each wave loads full 1 KB contiguous row-slabs (4 rows of a 16-row
//     group per phase) -> 1 KB DRAM granules, 2048 loading waves total.
//   - LDS transpose (32 KB, 2 buffers) -> each thread scans ONE channel
//     (CPT=1 state); tail work is split 4x across the block's waves.
//   - per-block early exit (256 ch) via __syncthreads_and each 16 rows.
//   - pipeline: issue loads for group g+2, write group g+1 regs->LDS
//     (vmcnt wait covers ~1 phase of latency), scan group g from LDS,
//     one barrier per phase.

constexpr int K_SPIKES = 3;
constexpr int BLOCK_CH = 256;  // channels per block == threads per block
constexpr int GROUP = 16;      // timestep rows per phase
constexpr int ROWS_PER_WAVE = 4;  // GROUP / 4 waves

__global__ __launch_bounds__(BLOCK_CH) void spikes_to_times_kernel(
    const float* __restrict__ in, float* __restrict__ out,
    int BN, int T, float dt) {
  // [buf][row_in_group][ch/4] : 2 * 16 * 64 * 16 B = 32 KB
  __shared__ float4 lds4[2][GROUP][BLOCK_CH / 4];
  const float* ldsF = reinterpret_cast<const float*>(&lds4[0][0][0]);

  const int tidx = threadIdx.x;
  const int wave = tidx >> 6;
  const int lane = tidx & 63;
  const int c0 = blockIdx.x * BLOCK_CH;
  const int c = c0 + tidx;  // this thread's scan/output channel
  const int ngroups = (T + GROUP - 1) / GROUP;

  // this lane's float4 channel base for loads (clamped for safety)
  int c4 = c0 + 4 * lane;
  if (c4 > BN - 4) c4 = BN - 4;

  float t0 = INFINITY, t1 = INFINITY, t2 = INFINITY;
  int cnt = 0;

  struct RowRegs { float4 r0, r1, r2, r3; };
  RowRegs rA, rB;

  // Load one row-slab: 1 KB contiguous per wave (64 lanes x float4).
#define LD(row)                                                          \
  (*reinterpret_cast<const float4*>(                                     \
      in + (size_t)(((row) < T) ? (row) : (T - 1)) * (size_t)BN + c4))

  // Issue the 4 row loads of group gi owned by this wave.
#define LOADG(dst, gi)                                                   \
  do {                                                                   \
    const int gg_ = ((gi) < ngroups) ? (gi) : (ngroups - 1);             \
    const int rb_ = gg_ * GROUP + wave;                                  \
    dst.r0 = LD(rb_);                                                    \
    dst.r1 = LD(rb_ + 4);                                                \
    dst.r2 = LD(rb_ + 8);                                                \
    dst.r3 = LD(rb_ + 12);                                               \
  } while (0)

  // Write this wave's 4 rows into LDS buffer `bf` (b128 stores).
#define WRITEG(src, bf)                                                  \
  do {                                                                   \
    lds4[bf][wave][lane] = src.r0;                                       \
    lds4[bf][wave + 4][lane] = src.r1;                                   \
    lds4[bf][wave + 8][lane] = src.r2;                                   \
    lds4[bf][wave + 12][lane] = src.r3;                                  \
  } while (0)

  // Scan 16 rows of group gi from LDS buffer `bf` for this thread's channel.
#define SCANG(bf, gi)                                                    \
  do {                                                                   \
    _Pragma("unroll") for (int r_ = 0; r_ < GROUP; ++r_) {               \
      const int ti_ = (gi)*GROUP + r_;                                   \
      const float v_ = ldsF[((bf)*GROUP + r_) * BLOCK_CH + tidx];        \
      const bool s_ = (v_ > 0.0f) && (ti_ < T);                          \
      const float tt_ = (float)ti_;                                      \
      if (s_ && cnt == 0) t0 = tt_;                                      \
      if (s_ && cnt == 1) t1 = tt_;                                      \
      if (s_ && cnt == 2) t2 = tt_;                                      \
      cnt += s_ ? 1 : 0;                                                 \
    }                                                                    \
  } while (0)

  // Prologue: group 0 -> LDS[0]; group 1 in flight in rB.
  LOADG(rA, 0);
  LOADG(rB, 1);
  WRITEG(rA, 0);
  __syncthreads();

  for (int g = 0; g < ngroups; g += 2) {
    // Phase g: LDS[0] holds g; rB holds g+1 (in flight).
    LOADG(rA, g + 2);   // issue next-next group
    WRITEG(rB, 1);      // vmcnt-waits rB only (rA stays in flight)
    SCANG(0, g);
    if (__syncthreads_and((cnt >= K_SPIKES) || (c >= BN))) break;

    // Phase g+1: LDS[1] holds g+1; rA holds g+2 (in flight).
    LOADG(rB, g + 3);
    WRITEG(rA, 0);
    SCANG(1, g + 1);
    if (__syncthreads_and((cnt >= K_SPIKES) || (c >= BN))) break;
  }

#undef LD
#undef LOADG
#undef WRITEG
#undef SCANG

  if (c < BN) {
    out[c] = t0 * dt;
    out[BN + c] = t1 * dt;
    out[2 * (size_t)BN + c] = t2 * dt;
  }
}

extern "C" void kernel_launch(void* const* d_in, const int* in_sizes, int n_in,
                              void* d_out, int out_size, void* d_ws, size_t ws_size,
                              hipStream_t stream) {
  const float* in = (const float*)d_in[0];
  float* out = (float*)d_out;

  const int BN = out_size / K_SPIKES;  // B * N channels
  const int T = in_sizes[0] / BN;      // timesteps

  const int grid = (BN + BLOCK_CH - 1) / BLOCK_CH;
  hipLaunchKernelGGL(spikes_to_times_kernel, dim3(grid), dim3(BLOCK_CH), 0,
                     stream, in, out, BN, T, 0.001f);
}

// Round 7
// 37.345 us; speedup vs baseline: 1.8945x; 1.7250x over previous
//
#include <hip/hip_runtime.h>
#include <cmath>

// SpikesToTimesDecoder: input [T, B, N] fp32 0/1 raster -> output [3, B, N]
// fp32 times (t * 0.001) of the first 3 spikes per channel, inf-padded.
//
// R1-R5 model: 256 B wave-granule column scans cap at ~3.3 TB/s chip service
// (R1/R2). R5's cooperative 1 KB-granule design was killed by __syncthreads'
// implicit vmcnt(0) drain. R6 fixed the drain (raw barrier + counted vmcnt)
// but had a flag bug: __all() was evaluated inside `if (lane==0)` -> reduced
// over one lane -> spurious early exit. This round fixes only that:
// compute wdone = __all(cnt>=3) under full wave exec, then lane 0 stores it.
//
// Structure: 4 waves cooperate on a 256-channel slab. Each wave loads full
// 1 KB contiguous row-slabs (2 rows of each 8-row group), LDS-transposes,
// each thread scans ONE channel (CPT=1 tail behavior). Non-draining pipeline:
//   - raw __builtin_amdgcn_s_barrier() (no vmcnt drain)
//   - counted `s_waitcnt vmcnt(6)`: 4 groups in flight x 2 loads/wave;
//     waiting the oldest group leaves 3 groups (6 loads) outstanding
//   - sched_barrier(0) pins around the waits
//   - early exit via LDS flags read post-barrier (block-uniform)
// Phase p: issue group p+4; vmcnt(6); ds_write group p+1; check flags;
// scan group p; set flag; lgkmcnt(0); s_barrier.

constexpr int K_SPIKES = 3;
constexpr int BLOCK_CH = 256;   // channels per block == threads per block
constexpr int GROUP = 8;        // timestep rows per phase
constexpr int RPW = 2;          // rows per wave per group (GROUP / 4 waves)

__global__ __launch_bounds__(BLOCK_CH) void spikes_to_times_kernel(
    const float* __restrict__ in, float* __restrict__ out,
    int BN, int T, float dt) {
  // [buf][row_in_group][ch/4] : 2 * 8 * 64 * 16 B = 16 KB
  __shared__ float4 lds4[2][GROUP][BLOCK_CH / 4];
  __shared__ int flagsDone[4] __attribute__((aligned(16)));
  const float* ldsF = reinterpret_cast<const float*>(&lds4[0][0][0]);

  const int tidx = threadIdx.x;
  const int wave = tidx >> 6;
  const int lane = tidx & 63;
  const int c0 = blockIdx.x * BLOCK_CH;
  const int c = c0 + tidx;  // this thread's scan/output channel
  const int ngroups = (T + GROUP - 1) / GROUP;

  int c4 = c0 + 4 * lane;  // this lane's float4 base for row loads
  if (c4 > BN - 4) c4 = BN - 4;

  float t0 = INFINITY, t1 = INFINITY, t2 = INFINITY;
  int cnt = 0;

  float4 q0a, q0b, q1a, q1b, q2a, q2b, q3a, q3b;

  // Issue this wave's 2 row loads (1 KB contiguous each) of group gi.
#define LOADG(A_, B_, gi)                                                  \
  do {                                                                     \
    const int gg_ = ((gi) < ngroups) ? (gi) : (ngroups - 1);               \
    int r0_ = gg_ * GROUP + wave * RPW;                                    \
    if (r0_ > T - RPW) r0_ = T - RPW;                                      \
    A_ = *reinterpret_cast<const float4*>(in + (size_t)r0_ * BN + c4);     \
    B_ = *reinterpret_cast<const float4*>(in + (size_t)(r0_ + 1) * BN + c4); \
  } while (0)

  // Counted wait: retire the oldest in-flight group, keep 3 groups (6 loads).
#define VMWAIT6()                                                          \
  do {                                                                     \
    __builtin_amdgcn_sched_barrier(0);                                     \
    asm volatile("s_waitcnt vmcnt(6)" ::: "memory");                       \
    __builtin_amdgcn_sched_barrier(0);                                     \
  } while (0)

#define WRITEG(A_, B_, bf)                                                 \
  do {                                                                     \
    lds4[bf][wave * RPW][lane] = A_;                                       \
    lds4[bf][wave * RPW + 1][lane] = B_;                                   \
  } while (0)

  // Scan GROUP rows of group gi from LDS buffer bf for this channel.
#define SCANG(bf, gi)                                                      \
  do {                                                                     \
    _Pragma("unroll") for (int r_ = 0; r_ < GROUP; ++r_) {                 \
      const int ti_ = (gi)*GROUP + r_;                                     \
      const float v_ = ldsF[((bf)*GROUP + r_) * BLOCK_CH + tidx];          \
      const bool s_ = (v_ > 0.0f) && (ti_ < T);                            \
      const float tt_ = (float)ti_;                                        \
      if (s_ && cnt == 0) t0 = tt_;                                        \
      if (s_ && cnt == 1) t1 = tt_;                                        \
      if (s_ && cnt == 2) t2 = tt_;                                        \
      cnt += s_ ? 1 : 0;                                                   \
    }                                                                      \
  } while (0)

  // Non-draining end-of-phase: commit my LDS writes, raw barrier, pin.
#define ENDPHASE()                                                         \
  do {                                                                     \
    asm volatile("s_waitcnt lgkmcnt(0)" ::: "memory");                     \
    __builtin_amdgcn_s_barrier();                                          \
    __builtin_amdgcn_sched_barrier(0);                                     \
  } while (0)

#define PHASE(p, IA_, IB_, WA_, WB_, ldsW, ldsS)                           \
  do {                                                                     \
    LOADG(IA_, IB_, (p) + 4); /* issue group p+4 into R[p%4] */            \
    VMWAIT6();                /* group p+1's loads retired */              \
    WRITEG(WA_, WB_, ldsW);   /* R[(p+1)%4] -> LDS[(p+1)%2] */             \
    if (flagsDone[0] & flagsDone[1] & flagsDone[2] & flagsDone[3])         \
      goto done;              /* uniform: flags from previous phase */     \
    SCANG(ldsS, (p));         /* scan group p */                           \
    {                                                                      \
      const bool wdone_ = __all(cnt >= K_SPIKES); /* FULL wave exec */     \
      if (lane == 0) flagsDone[wave] = wdone_ ? 1 : 0;                     \
    }                                                                      \
    ENDPHASE();                                                            \
  } while (0)

  // ---- prologue: groups 0..3 in flight; group 0 -> LDS[0] ----
  if (tidx < 4) flagsDone[tidx] = 0;
  LOADG(q0a, q0b, 0);
  LOADG(q1a, q1b, 1);
  LOADG(q2a, q2b, 2);
  LOADG(q3a, q3b, 3);
  VMWAIT6();  // retire group 0 (6 = groups 1..3 outstanding)
  WRITEG(q0a, q0b, 0);
  ENDPHASE();

  // ---- main loop: 4-phase unroll (reg rotation 4, LDS rotation 2) ----
  for (int p = 0; p < ngroups; p += 4) {
    PHASE(p + 0, q0a, q0b, q1a, q1b, 1, 0);
    PHASE(p + 1, q1a, q1b, q2a, q2b, 0, 1);
    PHASE(p + 2, q2a, q2b, q3a, q3b, 1, 0);
    PHASE(p + 3, q3a, q3b, q0a, q0b, 0, 1);
  }

done:
#undef LOADG
#undef VMWAIT6
#undef WRITEG
#undef SCANG
#undef ENDPHASE
#undef PHASE

  if (c < BN) {
    out[c] = t0 * dt;
    out[BN + c] = t1 * dt;
    out[2 * (size_t)BN + c] = t2 * dt;
  }
}

extern "C" void kernel_launch(void* const* d_in, const int* in_sizes, int n_in,
                              void* d_out, int out_size, void* d_ws, size_t ws_size,
                              hipStream_t stream) {
  const float* in = (const float*)d_in[0];
  float* out = (float*)d_out;

  const int BN = out_size / K_SPIKES;  // B * N channels
  const int T = in_sizes[0] / BN;      // timesteps

  const int grid = (BN + BLOCK_CH - 1) / BLOCK_CH;
  hipLaunchKernelGGL(spikes_to_times_kernel, dim3(grid), dim3(BLOCK_CH), 0,
                     stream, in, out, BN, T, 0.001f);
}